// Round 5
// baseline (170.161 us; speedup 1.0000x reference)
//
#include <hip/hip_runtime.h>
#include <math.h>

#define BS 8
#define NPTS 16384
#define C 32
#define K 256
#define KNNK 16
#define NBINS 512
#define BINW 0.00025f
#define CAP 4096

typedef float f32x4 __attribute__((ext_vector_type(4)));
typedef __bf16 bf16x8 __attribute__((ext_vector_type(8)));
union U16x8 { int4 i; bf16x8 v; unsigned short u[8]; };

// ---------------------------------------------------------------------------
// Phase 0: convert W (fp32 [32][256], first 32 rows of W_regress) into
// MFMA B-operand fragments, split-bf16 (hi = truncate, lo = truncate(f-hi)).
// B-frag layout (16x16x32): lane=quad*16+col holds B[k=quad*8+j][n=tile*16+col].
// Also zeroes the global keypoint accumulators (d_ws is poisoned 0xAA).
// Pooling head (W_pool) is mathematically unused: its logit contribution is
// constant over n and cancels in the per-graph softmax.
// ---------------------------------------------------------------------------
__global__ __launch_bounds__(256) void k_wprep(
    const float* __restrict__ Wr, unsigned short* __restrict__ Whi,
    unsigned short* __restrict__ Wlo, float* __restrict__ acc) {
  int slot = blockIdx.x * 256 + threadIdx.x;   // 1024 slots = 16 tiles x 64 lanes
  int tile = slot >> 6, lane = slot & 63;
  int quad = lane >> 4, col = lane & 15;
#pragma unroll
  for (int j = 0; j < 8; j++) {
    float v = Wr[(quad * 8 + j) * K + tile * 16 + col];
    unsigned u = __float_as_uint(v);
    unsigned hb = u >> 16;
    float hf = __uint_as_float(hb << 16);
    unsigned lb = __float_as_uint(v - hf) >> 16;
    Whi[slot * 8 + j] = (unsigned short)hb;
    Wlo[slot * 8 + j] = (unsigned short)lb;
  }
#pragma unroll
  for (int j = 0; j < 8; j++) acc[slot * 8 + j] = 0.f;   // 8192 floats total
}

// ---------------------------------------------------------------------------
// Phase 1: MFMA logit GEMM + exp + weighted position accumulation.
// Split-bf16: L = A_lo*B_hi + A_hi*B_lo + A_hi*B_hi (fp32 MFMA accum).
// delta-L ~ 3e-4 random per (n,k) -> keypoint shift ~2.5e-6 -> KNN flip
// expectation ~0.002 (fp32 path that passed is ~1e-7; same regime).
// Block = 256 thr (4 waves) x 128-point chunk. Wave (h=w&1, nh=w>>1):
// kp-half h (8 kp-tiles, B-frags in regs), n-half nh (4 n-tiles of 16 pts).
// A loaded per-lane coalesced from global (fp32), split in-regs (no SGPR
// ILP cap, unlike the round-2/4 scalar-load scheme). Per-graph merge via
// fp32 atomicAdd into acc[b][kp][{sum_e,x,y,z}] (order-independent enough).
// ---------------------------------------------------------------------------
__global__ __launch_bounds__(256) void k_logits(
    const float* __restrict__ f, const float* __restrict__ pos,
    const unsigned short* __restrict__ Whi, const unsigned short* __restrict__ Wlo,
    float* __restrict__ acc) {
  int b = blockIdx.x >> 7;          // 128 blocks per graph
  int r = blockIdx.x & 127;
  int pbase = b * NPTS + r * 128;
  int t = threadIdx.x;
  int w = t >> 6, lane = t & 63;
  int h = w & 1, nh = w >> 1;
  int quad = lane >> 4, col = lane & 15;

  __shared__ float4 posLDS[128];
  __shared__ float4 fm[2][256];

  // stage pos chunk (128 pts x 12 B) -> padded float4 via LDS repack
  float* rawf = (float*)&fm[0][0];
  if (t < 96) ((float4*)rawf)[t] = ((const float4*)(pos + (size_t)pbase * 3))[t];
  __syncthreads();
  float4 myp;
  if (t < 128) myp = make_float4(rawf[t * 3], rawf[t * 3 + 1], rawf[t * 3 + 2], 0.f);
  __syncthreads();
  if (t < 128) posLDS[t] = myp;

  // B fragments for this wave's kp-half (8 tiles, hi+lo)
  U16x8 Bh[8], Bl[8];
  const int4* wh4 = (const int4*)Whi;
  const int4* wl4 = (const int4*)Wlo;
#pragma unroll
  for (int jt = 0; jt < 8; jt++) {
    int slot = (h * 8 + jt) * 64 + lane;
    Bh[jt].i = wh4[slot];
    Bl[jt].i = wl4[slot];
  }
  float acce[8], accx[8], accy[8], accz[8];
#pragma unroll
  for (int jt = 0; jt < 8; jt++) { acce[jt] = 0.f; accx[jt] = 0.f; accy[jt] = 0.f; accz[jt] = 0.f; }
  __syncthreads();

#pragma unroll 1
  for (int nt = nh * 4; nt < nh * 4 + 4; nt++) {
    // A fragment: lane holds A[m=col][k=quad*8+j] = f[pt][ch], fp32 -> hi/lo
    const float* fb = f + ((size_t)(pbase + nt * 16 + col)) * C + quad * 8;
    float4 a0 = *(const float4*)fb;
    float4 a1 = *(const float4*)(fb + 4);
    float av[8] = {a0.x, a0.y, a0.z, a0.w, a1.x, a1.y, a1.z, a1.w};
    U16x8 Ah, Al;
#pragma unroll
    for (int j = 0; j < 8; j++) {
      unsigned u = __float_as_uint(av[j]);
      unsigned hb = u >> 16;
      float hf = __uint_as_float(hb << 16);
      unsigned lb = __float_as_uint(av[j] - hf) >> 16;
      Ah.u[j] = (unsigned short)hb;
      Al.u[j] = (unsigned short)lb;
    }
    float4 pr0 = posLDS[nt * 16 + quad * 4 + 0];
    float4 pr1 = posLDS[nt * 16 + quad * 4 + 1];
    float4 pr2 = posLDS[nt * 16 + quad * 4 + 2];
    float4 pr3 = posLDS[nt * 16 + quad * 4 + 3];
#pragma unroll
    for (int jt = 0; jt < 8; jt++) {
      f32x4 d = {0.f, 0.f, 0.f, 0.f};
      d = __builtin_amdgcn_mfma_f32_16x16x32_bf16(Al.v, Bh[jt].v, d, 0, 0, 0);
      d = __builtin_amdgcn_mfma_f32_16x16x32_bf16(Ah.v, Bl[jt].v, d, 0, 0, 0);
      d = __builtin_amdgcn_mfma_f32_16x16x32_bf16(Ah.v, Bh[jt].v, d, 0, 0, 0);
      // C/D layout: col=lane&15 (kp), row=quad*4+reg (pt)  [m89-verified]
      float e0 = __expf(d[0]), e1 = __expf(d[1]), e2 = __expf(d[2]), e3 = __expf(d[3]);
      acce[jt] += (e0 + e1) + (e2 + e3);
      accx[jt] += e0 * pr0.x + e1 * pr1.x + e2 * pr2.x + e3 * pr3.x;
      accy[jt] += e0 * pr0.y + e1 * pr1.y + e2 * pr2.y + e3 * pr3.y;
      accz[jt] += e0 * pr0.z + e1 * pr1.z + e2 * pr2.z + e3 * pr3.z;
    }
  }

  // reduce across quads (lane bits 4,5); kp = lane&15 preserved
#pragma unroll
  for (int jt = 0; jt < 8; jt++) {
    acce[jt] += __shfl_xor(acce[jt], 16); acce[jt] += __shfl_xor(acce[jt], 32);
    accx[jt] += __shfl_xor(accx[jt], 16); accx[jt] += __shfl_xor(accx[jt], 32);
    accy[jt] += __shfl_xor(accy[jt], 16); accy[jt] += __shfl_xor(accy[jt], 32);
    accz[jt] += __shfl_xor(accz[jt], 16); accz[jt] += __shfl_xor(accz[jt], 32);
  }
  if (lane < 16) {
#pragma unroll
    for (int jt = 0; jt < 8; jt++)
      fm[nh][h * 128 + jt * 16 + lane] = make_float4(acce[jt], accx[jt], accy[jt], accz[jt]);
  }
  __syncthreads();
  float4 v0 = fm[0][t], v1 = fm[1][t];
  float* ap = acc + ((size_t)(b * 256 + t)) * 4;
  atomicAdd(ap + 0, v0.x + v1.x);
  atomicAdd(ap + 1, v0.y + v1.y);
  atomicAdd(ap + 2, v0.z + v1.z);
  atomicAdd(ap + 3, v0.w + v1.w);
}

// ---------------------------------------------------------------------------
// Phase 2 (fused, one block per graph, 1024 threads): keypoints from acc,
// centroid + maxdiam, centroid histogram (catch-all bin skipped), exact
// candidate radius (triangle inequality), LDS compaction, exact top-16.
// Global-scan fallback if the filter degenerates -- always correct.
// ---------------------------------------------------------------------------
__global__ __launch_bounds__(1024) void k_graph(
    const float* __restrict__ pos, const float* __restrict__ acc,
    int* __restrict__ knn) {
  int b = blockIdx.x;
  int t = threadIdx.x;
  int lane = t & 63, wave = t >> 6;

  __shared__ float kxs[256], kys[256], kzs[256];
  __shared__ float wred[16][3];
  __shared__ float bc[6];          // cx, cy, cz, maxdiam, Rf2
  __shared__ unsigned hist[NBINS];
  __shared__ unsigned lcnt, ovf;
  __shared__ float cxs[CAP], cys[CAP], czs[CAP];
  __shared__ int cis[CAP];

  if (t < 256) {
    const float4 a = ((const float4*)acc)[b * 256 + t];
    float inv = 1.f / a.x;
    kxs[t] = a.y * inv; kys[t] = a.z * inv; kzs[t] = a.w * inv;
  }
  for (int i = t; i < NBINS; i += 1024) hist[i] = 0;
  if (t == 0) { lcnt = 0; ovf = 0; }
  __syncthreads();

  // --- centroid ---
  float sx = 0.f, sy = 0.f, sz = 0.f;
  if (t < 256) { sx = kxs[t]; sy = kys[t]; sz = kzs[t]; }
#pragma unroll
  for (int off = 32; off; off >>= 1) {
    sx += __shfl_xor(sx, off, 64);
    sy += __shfl_xor(sy, off, 64);
    sz += __shfl_xor(sz, off, 64);
  }
  if (lane == 0) { wred[wave][0] = sx; wred[wave][1] = sy; wred[wave][2] = sz; }
  __syncthreads();
  if (t == 0) {
    float X = 0.f, Y = 0.f, Z = 0.f;
#pragma unroll
    for (int i = 0; i < 16; i++) { X += wred[i][0]; Y += wred[i][1]; Z += wred[i][2]; }
    bc[0] = X / K; bc[1] = Y / K; bc[2] = Z / K;
  }
  __syncthreads();
  float cx = bc[0], cy = bc[1], cz = bc[2];
  // --- max keypoint distance from centroid ---
  float md = 0.f;
  if (t < 256) {
    float dx = kxs[t] - cx, dy = kys[t] - cy, dz = kzs[t] - cz;
    md = dx * dx + dy * dy + dz * dz;
  }
#pragma unroll
  for (int off = 32; off; off >>= 1) md = fmaxf(md, __shfl_xor(md, off, 64));
  if (lane == 0) wred[wave][0] = md;
  __syncthreads();
  if (t == 0) {
    float m = 0.f;
#pragma unroll
    for (int i = 0; i < 16; i++) m = fmaxf(m, wred[i][0]);
    bc[3] = sqrtf(m);
  }
  __syncthreads();

  // --- histogram (in-range bins only; ~4 loads in flight) ---
#pragma unroll 4
  for (int i = 0; i < 16; i++) {
    int p = b * NPTS + i * 1024 + t;
    float dx = pos[p * 3 + 0] - cx, dy = pos[p * 3 + 1] - cy, dz = pos[p * 3 + 2] - cz;
    float d2 = dx * dx + dy * dy + dz * dz;
    int bin = (int)(d2 * (1.0f / BINW));
    if (bin < NBINS - 1) atomicAdd(&hist[bin], 1u);
  }
  __syncthreads();

  // --- radius: T >= d16(centroid); R = T + 2*maxdiam (exact bound) ---
  if (t == 0) {
    unsigned cum = 0; float T2 = -1.f;
    for (int i = 0; i < NBINS - 1; i++) {
      cum += hist[i];
      if (cum >= KNNK) { T2 = (i + 1) * BINW; break; }
    }
    if (T2 < 0.f) bc[4] = 3.0e38f;
    else {
      float Rf = sqrtf(T2) + 2.f * bc[3];
      bc[4] = Rf * Rf;
    }
  }
  __syncthreads();
  float r2 = bc[4];

  // --- compact candidates into LDS ---
#pragma unroll 4
  for (int i = 0; i < 16; i++) {
    int pl = i * 1024 + t;
    int p = b * NPTS + pl;
    float px = pos[p * 3 + 0], py = pos[p * 3 + 1], pz = pos[p * 3 + 2];
    float dx = px - cx, dy = py - cy, dz = pz - cz;
    float d2 = dx * dx + dy * dy + dz * dz;
    if (d2 <= r2) {
      unsigned u = atomicAdd(&lcnt, 1u);
      if (u < CAP) { cxs[u] = px; cys[u] = py; czs[u] = pz; cis[u] = pl; }
      else ovf = 1;
    }
  }
  __syncthreads();

  // --- exact top-16 per keypoint ---
  if (t < 256) {
    float kx = kxs[t], ky = kys[t], kz = kzs[t];
    float dd[KNNK]; int ii[KNNK];
#pragma unroll
    for (int j = 0; j < KNNK; j++) { dd[j] = 1e30f; ii[j] = 0; }
    float mx = 1e30f;
    if (!ovf) {
      int n = (int)lcnt;
      for (int j = 0; j < n; j++) {
        float dx = kx - cxs[j], dy = ky - cys[j], dz = kz - czs[j];
        float d2 = dx * dx + dy * dy + dz * dz;
        if (d2 < mx) {
          int sm = 0; float bv = dd[0];
#pragma unroll
          for (int s = 1; s < KNNK; s++) if (dd[s] > bv) { bv = dd[s]; sm = s; }
#pragma unroll
          for (int s = 0; s < KNNK; s++) if (s == sm) { dd[s] = d2; ii[s] = cis[j]; }
          mx = dd[0];
#pragma unroll
          for (int s = 1; s < KNNK; s++) mx = fmaxf(mx, dd[s]);
        }
      }
    } else {
      for (int j = 0; j < NPTS; j++) {
        const float* pp = pos + (size_t)(b * NPTS + j) * 3;
        float dx = kx - pp[0], dy = ky - pp[1], dz = kz - pp[2];
        float d2 = dx * dx + dy * dy + dz * dz;
        if (d2 < mx) {
          int sm = 0; float bv = dd[0];
#pragma unroll
          for (int s = 1; s < KNNK; s++) if (dd[s] > bv) { bv = dd[s]; sm = s; }
#pragma unroll
          for (int s = 0; s < KNNK; s++) if (s == sm) { dd[s] = d2; ii[s] = j; }
          mx = dd[0];
#pragma unroll
          for (int s = 1; s < KNNK; s++) mx = fmaxf(mx, dd[s]);
        }
      }
    }
    for (int j = 0; j < KNNK; j++) knn[((size_t)(b * K + t)) * KNNK + j] = ii[j];
  }
}

// ---------------------------------------------------------------------------
// Phase 3: gather 16 neighbor feature rows, mean, 32x32 linear.
// ---------------------------------------------------------------------------
__global__ __launch_bounds__(256) void k_extract(
    const float* __restrict__ f, const int* __restrict__ knn,
    const float* __restrict__ We, float* __restrict__ out) {
  __shared__ float P[8][C + 1];
  int tid = threadIdx.x;
  int kp = tid >> 5, c = tid & 31;
  int gk = blockIdx.x * 8 + kp;   // 0..2047
  int b = gk >> 8;
  float s = 0.f;
#pragma unroll
  for (int j = 0; j < KNNK; j++) {
    int pl = knn[(size_t)gk * KNNK + j];
    s += f[((size_t)(b * NPTS + pl)) * C + c];
  }
  P[kp][c] = s * (1.f / KNNK);
  __syncthreads();
  float r = 0.f;
#pragma unroll
  for (int cc = 0; cc < C; cc++) r += P[kp][cc] * We[cc * C + c];
  out[(size_t)gk * C + c] = r;
}

extern "C" void kernel_launch(void* const* d_in, const int* in_sizes, int n_in,
                              void* d_out, int out_size, void* d_ws, size_t ws_size,
                              hipStream_t stream) {
  const float* f   = (const float*)d_in[0];
  const float* pos = (const float*)d_in[1];
  // d_in[2] = W_pool: mathematically unused (bias cancels in segment softmax)
  const float* Wr  = (const float*)d_in[3];
  const float* We  = (const float*)d_in[4];
  float* out = (float*)d_out;

  char* ws = (char*)d_ws;
  float*          acc = (float*)(ws + 0);              // [8][256][4] f32 = 32768 B
  unsigned short* Whi = (unsigned short*)(ws + 32768); // [16][64][8] bf16 = 16384 B
  unsigned short* Wlo = (unsigned short*)(ws + 49152); // 16384 B
  int*            knn = (int*)(ws + 65536);            // [8][256][16] i32 = 131072 B

  k_wprep  <<<dim3(4),    dim3(256),  0, stream>>>(Wr, Whi, Wlo, acc);
  k_logits <<<dim3(1024), dim3(256),  0, stream>>>(f, pos, Whi, Wlo, acc);
  k_graph  <<<dim3(BS),   dim3(1024), 0, stream>>>(pos, acc, knn);
  k_extract<<<dim3(256),  dim3(256),  0, stream>>>(f, knn, We, out);
}

// Round 6
// 132.665 us; speedup vs baseline: 1.2826x; 1.2826x over previous
//
#include <hip/hip_runtime.h>
#include <math.h>

#define BS 8
#define NPTS 16384
#define C 32
#define K 256
#define KNNK 16
#define NBINS 512
#define BINW 0.00025f
#define CAP 4096
#define NSPL 64          // point-splits per graph in k_logits

typedef float f32x4 __attribute__((ext_vector_type(4)));
typedef __bf16 bf16x8 __attribute__((ext_vector_type(8)));
union U16x8 { int4 i; bf16x8 v; unsigned short u[8]; };

// ---------------------------------------------------------------------------
// Phase 1: MFMA logit GEMM + exp + weighted position accumulation.
// Split-bf16: L = A_lo*B_hi + A_hi*B_lo + A_hi*B_hi (fp32 MFMA accum);
// verified round 5: identical KNN sets vs fp32 path (same absmax).
// Pooling head (W_pool) unused: its logit term is constant over n and cancels
// in the per-graph softmax. Block = 256 thr (4 waves) x 256-pt chunk; wave
// (h=w&1) takes kp-half, (nh=w>>1) takes n-half. B-frags loaded directly from
// fp32 Wr (L2-resident, once per block) and split in-regs. Merge via plain
// per-block partial stores -- round 5's cross-XCD atomicAdd line ping-pong
// (~60us) is eliminated.
// ---------------------------------------------------------------------------
__global__ __launch_bounds__(256, 2) void k_logits(
    const float* __restrict__ f, const float* __restrict__ pos,
    const float* __restrict__ Wr, float* __restrict__ partials) {
  int b = blockIdx.x >> 6;          // 64 blocks per graph
  int r = blockIdx.x & 63;
  int pbase = b * NPTS + r * 256;
  int t = threadIdx.x;
  int w = t >> 6, lane = t & 63;
  int h = w & 1, nh = w >> 1;
  int quad = lane >> 4, col = lane & 15;

  __shared__ float4 posLDS[256];
  __shared__ float4 fm[2][256];

  // stage pos chunk (256 pts x 12 B) -> padded float4 via LDS repack
  float* rawf = (float*)&fm[0][0];
  if (t < 192) ((float4*)rawf)[t] = ((const float4*)(pos + (size_t)pbase * 3))[t];
  __syncthreads();
  float4 myp = make_float4(rawf[t * 3], rawf[t * 3 + 1], rawf[t * 3 + 2], 0.f);
  __syncthreads();
  posLDS[t] = myp;

  // B fragments for this wave's kp-half (8 tiles), direct fp32 load + split.
  // B[k=quad*8+j][n=tile*16+col] = Wr[(quad*8+j)*K + tile*16+col]
  U16x8 Bh[8], Bl[8];
#pragma unroll
  for (int jt = 0; jt < 8; jt++) {
    int tile = h * 8 + jt;
#pragma unroll
    for (int j = 0; j < 8; j++) {
      float v = Wr[(quad * 8 + j) * K + tile * 16 + col];
      unsigned u = __float_as_uint(v);
      unsigned hb = u >> 16;
      float hf = __uint_as_float(hb << 16);
      unsigned lb = __float_as_uint(v - hf) >> 16;
      Bh[jt].u[j] = (unsigned short)hb;
      Bl[jt].u[j] = (unsigned short)lb;
    }
  }
  float acce[8], accx[8], accy[8], accz[8];
#pragma unroll
  for (int jt = 0; jt < 8; jt++) { acce[jt] = 0.f; accx[jt] = 0.f; accy[jt] = 0.f; accz[jt] = 0.f; }

#pragma unroll 1
  for (int nt = nh * 8; nt < nh * 8 + 8; nt++) {
    // A fragment: lane holds A[m=col][k=quad*8+j] = f[pt][ch], fp32 -> hi/lo
    const float* fb = f + ((size_t)(pbase + nt * 16 + col)) * C + quad * 8;
    float4 a0 = *(const float4*)fb;
    float4 a1 = *(const float4*)(fb + 4);
    float av[8] = {a0.x, a0.y, a0.z, a0.w, a1.x, a1.y, a1.z, a1.w};
    U16x8 Ah, Al;
#pragma unroll
    for (int j = 0; j < 8; j++) {
      unsigned u = __float_as_uint(av[j]);
      unsigned hb = u >> 16;
      float hf = __uint_as_float(hb << 16);
      unsigned lb = __float_as_uint(av[j] - hf) >> 16;
      Ah.u[j] = (unsigned short)hb;
      Al.u[j] = (unsigned short)lb;
    }
    float4 pr0 = posLDS[nt * 16 + quad * 4 + 0];
    float4 pr1 = posLDS[nt * 16 + quad * 4 + 1];
    float4 pr2 = posLDS[nt * 16 + quad * 4 + 2];
    float4 pr3 = posLDS[nt * 16 + quad * 4 + 3];
#pragma unroll
    for (int jt = 0; jt < 8; jt++) {
      f32x4 d = {0.f, 0.f, 0.f, 0.f};
      d = __builtin_amdgcn_mfma_f32_16x16x32_bf16(Al.v, Bh[jt].v, d, 0, 0, 0);
      d = __builtin_amdgcn_mfma_f32_16x16x32_bf16(Ah.v, Bl[jt].v, d, 0, 0, 0);
      d = __builtin_amdgcn_mfma_f32_16x16x32_bf16(Ah.v, Bh[jt].v, d, 0, 0, 0);
      // C/D layout: col=lane&15 (kp), row=quad*4+reg (pt)  [m89-verified]
      float e0 = __expf(d[0]), e1 = __expf(d[1]), e2 = __expf(d[2]), e3 = __expf(d[3]);
      acce[jt] += (e0 + e1) + (e2 + e3);
      accx[jt] += e0 * pr0.x + e1 * pr1.x + e2 * pr2.x + e3 * pr3.x;
      accy[jt] += e0 * pr0.y + e1 * pr1.y + e2 * pr2.y + e3 * pr3.y;
      accz[jt] += e0 * pr0.z + e1 * pr1.z + e2 * pr2.z + e3 * pr3.z;
    }
  }

  // reduce across quads (lane bits 4,5); kp slot = h*128 + jt*16 + (lane&15)
#pragma unroll
  for (int jt = 0; jt < 8; jt++) {
    acce[jt] += __shfl_xor(acce[jt], 16); acce[jt] += __shfl_xor(acce[jt], 32);
    accx[jt] += __shfl_xor(accx[jt], 16); accx[jt] += __shfl_xor(accx[jt], 32);
    accy[jt] += __shfl_xor(accy[jt], 16); accy[jt] += __shfl_xor(accy[jt], 32);
    accz[jt] += __shfl_xor(accz[jt], 16); accz[jt] += __shfl_xor(accz[jt], 32);
  }
  __syncthreads();   // fm[0] was aliased as pos staging; all reads done
  if (lane < 16) {
#pragma unroll
    for (int jt = 0; jt < 8; jt++)
      fm[nh][h * 128 + jt * 16 + lane] = make_float4(acce[jt], accx[jt], accy[jt], accz[jt]);
  }
  __syncthreads();
  float4 v0 = fm[0][t], v1 = fm[1][t];
  float4* po = (float4*)partials;
  po[(size_t)blockIdx.x * 256 + t] =
      make_float4(v0.x + v1.x, v0.y + v1.y, v0.z + v1.z, v0.w + v1.w);
}

// ---------------------------------------------------------------------------
// Phase 2 (fused, one block per graph, 1024 threads):
//   M. merge 64 split-partials -> keypoints (coalesced, 4-way split-sum)
//   A. keypoint centroid + max keypoint-centroid distance
//   B. histogram of d2(point, centroid) -- catch-all bin skipped
//   C. radius: T >= d16(centroid); R = T + 2*maxdiam (triangle-ineq exact);
//      degenerates to R=inf -> global-scan fallback (always correct)
//   D. compact candidates (~40/graph) into LDS
//   E. exact top-16 per keypoint over LDS candidates
// ---------------------------------------------------------------------------
__global__ __launch_bounds__(1024) void k_graph(
    const float* __restrict__ pos, const float* __restrict__ partials,
    int* __restrict__ knn) {
  int b = blockIdx.x;
  int t = threadIdx.x;
  int lane = t & 63, wave = t >> 6;

  __shared__ float4 mred[4][256];
  __shared__ float kxs[256], kys[256], kzs[256];
  __shared__ float wred[16][3];
  __shared__ float bc[6];          // cx, cy, cz, maxdiam, Rf2
  __shared__ unsigned hist[NBINS];
  __shared__ unsigned lcnt, ovf;
  __shared__ float cxs[CAP], cys[CAP], czs[CAP];
  __shared__ int cis[CAP];

  // --- M: merge partials ---
  {
    int kp = t & 255, q = t >> 8;   // q in 0..3, 16 splits each
    const float4* po = (const float4*)partials;
    float sl = 0.f, sx = 0.f, sy = 0.f, sz = 0.f;
#pragma unroll 4
    for (int j = 0; j < 16; j++) {
      float4 v = po[((size_t)(b * NSPL + q * 16 + j)) * 256 + kp];
      sl += v.x; sx += v.y; sy += v.z; sz += v.w;
    }
    mred[q][kp] = make_float4(sl, sx, sy, sz);
  }
  for (int i = t; i < NBINS; i += 1024) hist[i] = 0;
  if (t == 0) { lcnt = 0; ovf = 0; }
  __syncthreads();
  if (t < 256) {
    float4 a0 = mred[0][t], a1 = mred[1][t], a2 = mred[2][t], a3 = mred[3][t];
    float L = (a0.x + a1.x) + (a2.x + a3.x);
    float inv = 1.f / L;
    kxs[t] = ((a0.y + a1.y) + (a2.y + a3.y)) * inv;
    kys[t] = ((a0.z + a1.z) + (a2.z + a3.z)) * inv;
    kzs[t] = ((a0.w + a1.w) + (a2.w + a3.w)) * inv;
  }
  __syncthreads();

  // --- A: centroid ---
  float sx = 0.f, sy = 0.f, sz = 0.f;
  if (t < 256) { sx = kxs[t]; sy = kys[t]; sz = kzs[t]; }
#pragma unroll
  for (int off = 32; off; off >>= 1) {
    sx += __shfl_xor(sx, off, 64);
    sy += __shfl_xor(sy, off, 64);
    sz += __shfl_xor(sz, off, 64);
  }
  if (lane == 0) { wred[wave][0] = sx; wred[wave][1] = sy; wred[wave][2] = sz; }
  __syncthreads();
  if (t == 0) {
    float X = 0.f, Y = 0.f, Z = 0.f;
#pragma unroll
    for (int i = 0; i < 16; i++) { X += wred[i][0]; Y += wred[i][1]; Z += wred[i][2]; }
    bc[0] = X / K; bc[1] = Y / K; bc[2] = Z / K;
  }
  __syncthreads();
  float cx = bc[0], cy = bc[1], cz = bc[2];
  // --- A2: max keypoint distance from centroid ---
  float md = 0.f;
  if (t < 256) {
    float dx = kxs[t] - cx, dy = kys[t] - cy, dz = kzs[t] - cz;
    md = dx * dx + dy * dy + dz * dz;
  }
#pragma unroll
  for (int off = 32; off; off >>= 1) md = fmaxf(md, __shfl_xor(md, off, 64));
  if (lane == 0) wred[wave][0] = md;
  __syncthreads();
  if (t == 0) {
    float m = 0.f;
#pragma unroll
    for (int i = 0; i < 16; i++) m = fmaxf(m, wred[i][0]);
    bc[3] = sqrtf(m);
  }
  __syncthreads();

  // --- B: histogram (in-range bins only) ---
#pragma unroll 4
  for (int i = 0; i < 16; i++) {
    int p = b * NPTS + i * 1024 + t;
    float dx = pos[p * 3 + 0] - cx, dy = pos[p * 3 + 1] - cy, dz = pos[p * 3 + 2] - cz;
    float d2 = dx * dx + dy * dy + dz * dz;
    int bin = (int)(d2 * (1.0f / BINW));
    if (bin < NBINS - 1) atomicAdd(&hist[bin], 1u);
  }
  __syncthreads();

  // --- C: select radius ---
  if (t == 0) {
    unsigned cum = 0; float T2 = -1.f;
    for (int i = 0; i < NBINS - 1; i++) {
      cum += hist[i];
      if (cum >= KNNK) { T2 = (i + 1) * BINW; break; }
    }
    if (T2 < 0.f) bc[4] = 3.0e38f;
    else {
      float Rf = sqrtf(T2) + 2.f * bc[3];
      bc[4] = Rf * Rf;
    }
  }
  __syncthreads();
  float r2 = bc[4];

  // --- D: compact candidates into LDS ---
#pragma unroll 4
  for (int i = 0; i < 16; i++) {
    int pl = i * 1024 + t;
    int p = b * NPTS + pl;
    float px = pos[p * 3 + 0], py = pos[p * 3 + 1], pz = pos[p * 3 + 2];
    float dx = px - cx, dy = py - cy, dz = pz - cz;
    float d2 = dx * dx + dy * dy + dz * dz;
    if (d2 <= r2) {
      unsigned u = atomicAdd(&lcnt, 1u);
      if (u < CAP) { cxs[u] = px; cys[u] = py; czs[u] = pz; cis[u] = pl; }
      else ovf = 1;
    }
  }
  __syncthreads();

  // --- E: exact top-16 per keypoint ---
  if (t < 256) {
    float kx = kxs[t], ky = kys[t], kz = kzs[t];
    float dd[KNNK]; int ii[KNNK];
#pragma unroll
    for (int j = 0; j < KNNK; j++) { dd[j] = 1e30f; ii[j] = 0; }
    float mx = 1e30f;
    if (!ovf) {
      int n = (int)lcnt;
      for (int j = 0; j < n; j++) {
        float dx = kx - cxs[j], dy = ky - cys[j], dz = kz - czs[j];
        float d2 = dx * dx + dy * dy + dz * dz;
        if (d2 < mx) {
          int sm = 0; float bv = dd[0];
#pragma unroll
          for (int s = 1; s < KNNK; s++) if (dd[s] > bv) { bv = dd[s]; sm = s; }
#pragma unroll
          for (int s = 0; s < KNNK; s++) if (s == sm) { dd[s] = d2; ii[s] = cis[j]; }
          mx = dd[0];
#pragma unroll
          for (int s = 1; s < KNNK; s++) mx = fmaxf(mx, dd[s]);
        }
      }
    } else {
      for (int j = 0; j < NPTS; j++) {
        const float* pp = pos + (size_t)(b * NPTS + j) * 3;
        float dx = kx - pp[0], dy = ky - pp[1], dz = kz - pp[2];
        float d2 = dx * dx + dy * dy + dz * dz;
        if (d2 < mx) {
          int sm = 0; float bv = dd[0];
#pragma unroll
          for (int s = 1; s < KNNK; s++) if (dd[s] > bv) { bv = dd[s]; sm = s; }
#pragma unroll
          for (int s = 0; s < KNNK; s++) if (s == sm) { dd[s] = d2; ii[s] = j; }
          mx = dd[0];
#pragma unroll
          for (int s = 1; s < KNNK; s++) mx = fmaxf(mx, dd[s]);
        }
      }
    }
    for (int j = 0; j < KNNK; j++) knn[((size_t)(b * K + t)) * KNNK + j] = ii[j];
  }
}

// ---------------------------------------------------------------------------
// Phase 3: gather 16 neighbor feature rows, mean, 32x32 linear.
// ---------------------------------------------------------------------------
__global__ __launch_bounds__(256) void k_extract(
    const float* __restrict__ f, const int* __restrict__ knn,
    const float* __restrict__ We, float* __restrict__ out) {
  __shared__ float P[8][C + 1];
  int tid = threadIdx.x;
  int kp = tid >> 5, c = tid & 31;
  int gk = blockIdx.x * 8 + kp;   // 0..2047
  int b = gk >> 8;
  float s = 0.f;
#pragma unroll
  for (int j = 0; j < KNNK; j++) {
    int pl = knn[(size_t)gk * KNNK + j];
    s += f[((size_t)(b * NPTS + pl)) * C + c];
  }
  P[kp][c] = s * (1.f / KNNK);
  __syncthreads();
  float r = 0.f;
#pragma unroll
  for (int cc = 0; cc < C; cc++) r += P[kp][cc] * We[cc * C + c];
  out[(size_t)gk * C + c] = r;
}

extern "C" void kernel_launch(void* const* d_in, const int* in_sizes, int n_in,
                              void* d_out, int out_size, void* d_ws, size_t ws_size,
                              hipStream_t stream) {
  const float* f   = (const float*)d_in[0];
  const float* pos = (const float*)d_in[1];
  // d_in[2] = W_pool: mathematically unused (bias cancels in segment softmax)
  const float* Wr  = (const float*)d_in[3];
  const float* We  = (const float*)d_in[4];
  float* out = (float*)d_out;

  char* ws = (char*)d_ws;
  float* partials = (float*)(ws + 0);                    // [512][256][4] f32 = 2 MiB
  int*   knn      = (int*)(ws + (size_t)2 * 1024 * 1024);// [8][256][16] i32 = 128 KiB

  k_logits <<<dim3(BS * NSPL), dim3(256),  0, stream>>>(f, pos, Wr, partials);
  k_graph  <<<dim3(BS),        dim3(1024), 0, stream>>>(pos, partials, knn);
  k_extract<<<dim3(256),       dim3(256),  0, stream>>>(f, knn, We, out);
}